// Round 5
// baseline (1897.570 us; speedup 1.0000x reference)
//
#include <hip/hip_runtime.h>
#include <hip/hip_bf16.h>

#define D 128
typedef __hip_bfloat16 bf16;

static __device__ __forceinline__ float bf2f(bf16 v) { return __bfloat162float(v); }
// int access that adapts to int32 (f64=0) or int64 little-endian (f64=1) storage
static __device__ __forceinline__ int geti(const int* p, int k, int f64) {
    return f64 ? p[2 * k] : p[k];
}

// ---------- K0a: float-storage detector (bf16 vs f32) + zero ew_sum ----------
__global__ void k_detect_f(const void* __restrict__ embp, int m,
                           int* __restrict__ flagf, float* __restrict__ ew_sum) {
    int bad = 0;
    const bf16* e = (const bf16*)embp;
    for (int i = threadIdx.x; i < m; i += 256) {
        float f = bf2f(e[i]);
        if (!(fabsf(f) <= 100.f)) bad = 1;
    }
    __shared__ int sh;
    if (threadIdx.x == 0) { sh = 0; *ew_sum = 0.f; }
    __syncthreads();
    if (bad) atomicOr(&sh, 1);
    __syncthreads();
    if (threadIdx.x == 0) *flagf = sh;  // 1 = f32 storage, 0 = bf16 storage
}

// ---------- K0b: int-storage detector (int32 vs int64) ----------
__global__ void k_detect_i(const int* __restrict__ eix, int* __restrict__ flagi) {
    int nz = 0;
    for (int k = threadIdx.x; k < 4096; k += 256)
        if (eix[2 * k + 1] != 0) nz = 1;
    __shared__ int sh;
    if (threadIdx.x == 0) sh = 0;
    __syncthreads();
    if (nz) atomicOr(&sh, 1);
    __syncthreads();
    if (threadIdx.x == 0) *flagi = sh ? 0 : 1;  // 1 = int64 storage
}

// ---------- K0c: canonicalize the 19 float param tensors to f32 ----------
#define NCV 19
struct CvArgs { const void* s[NCV]; float* d[NCV]; int n[NCV]; };
__global__ void k_convert(CvArgs a, const int* __restrict__ flagf) {
    int f = *flagf;
    int b = blockIdx.x;
    const void* sp = a.s[b];
    float* dp = a.d[b];
    int m = a.n[b];
    if (f) {
        const float* s = (const float*)sp;
        for (int i = threadIdx.x; i < m; i += blockDim.x) dp[i] = s[i];
    } else {
        const bf16* s = (const bf16*)sp;
        for (int i = threadIdx.x; i < m; i += blockDim.x) dp[i] = bf2f(s[i]);
    }
}

// ---------- K0d: zero a float buffer ----------
__global__ void k_zerof(float* __restrict__ p, int cnt) {
    for (int i = blockIdx.x * blockDim.x + threadIdx.x; i < cnt; i += gridDim.x * blockDim.x)
        p[i] = 0.f;
}

// ---------- K1: sum of edge weights ----------
__global__ void k_ew_sum(const void* __restrict__ wp, int E, const int* __restrict__ flagf,
                         float* __restrict__ out) {
    int f = *flagf;
    float s = 0.f;
    for (int i = blockIdx.x * blockDim.x + threadIdx.x; i < E; i += gridDim.x * blockDim.x)
        s += f ? ((const float*)wp)[i] : bf2f(((const bf16*)wp)[i]);
    for (int o = 32; o > 0; o >>= 1) s += __shfl_down(s, o, 64);
    __shared__ float ls[4];
    if ((threadIdx.x & 63) == 0) ls[threadIdx.x >> 6] = s;
    __syncthreads();
    if (threadIdx.x == 0) atomicAdd(out, ls[0] + ls[1] + ls[2] + ls[3]);
}

// ---------- K2: layer-1 vocab tables EWl = emb@W1l + b1l, EWr = emb@W1r + b1r ----------
__global__ void k_tables(const float* __restrict__ emb,
                         const float* __restrict__ Wl, const float* __restrict__ bl,
                         const float* __restrict__ Wr, const float* __restrict__ br,
                         float* __restrict__ EWl, float* __restrict__ EWr) {
    int r = blockIdx.x, c = threadIdx.x;
    __shared__ float er[D];
    er[c] = emb[r * D + c];
    __syncthreads();
    float al = bl[c], ar = br[c];
    for (int k = 0; k < D; ++k) {
        float e = er[k];
        al += e * Wl[k * D + c];
        ar += e * Wr[k * D + c];
    }
    EWl[r * D + c] = al;
    EWr[r * D + c] = ar;
}

// ---------- K3: layer-1 edge kernel (one wave per edge incl. self loops) ----------
__global__ void __launch_bounds__(256) k_edge1(
    const int* __restrict__ nid, const int* __restrict__ eix, const void* __restrict__ ewp,
    const int* __restrict__ flagf, const int* __restrict__ flagi,
    const float* __restrict__ EWl, const float* __restrict__ EWr,
    const float* __restrict__ We, const float* __restrict__ att,
    const float* __restrict__ ew_sum, float invE, int E, int n,
    float* __restrict__ agg, float* __restrict__ ssum) {
    long idx = (long)blockIdx.x * blockDim.x + threadIdx.x;
    int e = (int)(idx >> 6);
    int lane = (int)(idx & 63);
    if (e >= E + n) return;
    int ff = *flagf, fi = *flagi;
    int s, d;
    float w;
    if (e < E) {
        s = geti(eix, e, fi);
        d = geti(eix, E + e, fi);
        w = ff ? ((const float*)ewp)[e] : bf2f(((const bf16*)ewp)[e]);
    } else {
        s = d = e - E;
        w = ew_sum[0] * invE;
    }
    int ts = geti(nid, s, fi), td = geti(nid, d, fi);
    const float2* L = (const float2*)EWl;
    const float2* R = (const float2*)EWr;
    float2 xl = L[ts * 64 + lane];
    float2 xr = R[td * 64 + lane];
    int c0 = 2 * lane, c1 = c0 + 1;
    float mx = xl.x + xr.x + w * We[c0];
    float my = xl.y + xr.y + w * We[c1];
    mx = mx >= 0.f ? mx : 0.2f * mx;
    my = my >= 0.f ? my : 0.2f * my;
    float p = mx * att[c0] + my * att[c1];
    for (int o = 1; o < 64; o <<= 1) p += __shfl_xor(p, o, 64);
    float ev = __expf(p);
    atomicAdd(&agg[(long)d * D + c0], ev * xl.x);
    atomicAdd(&agg[(long)d * D + c1], ev * xl.y);
    if (lane == 0) atomicAdd(&ssum[d], ev);
}

// ---------- K4: layer-1 epilogue -> h1 in d_out (dtype follows flagf) ----------
__global__ void __launch_bounds__(256) k_post1(
    const int* __restrict__ nid, const int* __restrict__ flagi, const int* __restrict__ flagf,
    const float* __restrict__ agg, const float* __restrict__ ssum,
    const float* __restrict__ emb, const float* __restrict__ bias,
    const float* __restrict__ g, const float* __restrict__ be,
    int n, void* __restrict__ h1) {
    int v = (int)(((long)blockIdx.x * blockDim.x + threadIdx.x) >> 6);
    int lane = threadIdx.x & 63;
    if (v >= n) return;
    int tv = geti(nid, v, *flagi);
    int c0 = 2 * lane, c1 = c0 + 1;
    float inv = 1.f / ssum[v];
    float vx = agg[(long)v * D + c0] * inv + bias[c0] + emb[tv * D + c0];
    float vy = agg[(long)v * D + c1] * inv + bias[c1] + emb[tv * D + c1];
    float s1 = vx + vy;
    for (int o = 1; o < 64; o <<= 1) s1 += __shfl_xor(s1, o, 64);
    float mu = s1 * (1.f / 128.f);
    float dx = vx - mu, dy = vy - mu;
    float s2 = dx * dx + dy * dy;
    for (int o = 1; o < 64; o <<= 1) s2 += __shfl_xor(s2, o, 64);
    float rstd = rsqrtf(s2 * (1.f / 128.f) + 1e-5f);
    float ox = dx * rstd * g[c0] + be[c0];
    float oy = dy * rstd * g[c1] + be[c1];
    if (*flagf) {
        ((float2*)h1)[(long)v * 64 + lane] = make_float2(ox, oy);
    } else {
        __hip_bfloat162 hb;
        hb.x = __float2bfloat16(ox);
        hb.y = __float2bfloat16(oy);
        ((__hip_bfloat162*)h1)[(long)v * 64 + lane] = hb;
    }
}

// ---------- K5: layer-2 GEMMs xl2 = h1@W2l + b2l, xr2 = h1@W2r + b2r (bf16 out) ----------
__global__ void __launch_bounds__(128) k_gemm2(
    const void* __restrict__ h1, const int* __restrict__ flagf,
    const float* __restrict__ Wl, const float* __restrict__ bl,
    const float* __restrict__ Wr, const float* __restrict__ br, int n,
    bf16* __restrict__ xl2, bf16* __restrict__ xr2) {
    const int BN = 16;
    __shared__ float xs[BN][D];
    int v0 = blockIdx.x * BN;
    int t = threadIdx.x;
    int ff = *flagf;
    for (int i = t; i < BN * D; i += 128) {
        int r = i >> 7, c = i & 127;
        int v = v0 + r;
        float x = 0.f;
        if (v < n)
            x = ff ? ((const float*)h1)[(long)v * D + c]
                   : bf2f(((const bf16*)h1)[(long)v * D + c]);
        xs[r][c] = x;
    }
    __syncthreads();
    int c = t;
    float accl[BN], accr[BN];
    float blc = bl[c], brc = br[c];
#pragma unroll
    for (int r = 0; r < BN; ++r) { accl[r] = blc; accr[r] = brc; }
    for (int k = 0; k < D; ++k) {
        float wl = Wl[k * D + c];
        float wr = Wr[k * D + c];
#pragma unroll
        for (int r = 0; r < BN; ++r) {
            float s = xs[r][k];
            accl[r] += s * wl;
            accr[r] += s * wr;
        }
    }
    for (int r = 0; r < BN; ++r) {
        int v = v0 + r;
        if (v < n) {
            xl2[(long)v * D + c] = __float2bfloat16(accl[r]);
            xr2[(long)v * D + c] = __float2bfloat16(accr[r]);
        }
    }
}

// ---------- K6: layer-2 edge kernel ----------
__global__ void __launch_bounds__(256) k_edge2(
    const int* __restrict__ eix, const void* __restrict__ ewp,
    const int* __restrict__ flagf, const int* __restrict__ flagi,
    const bf16* __restrict__ xl2, const bf16* __restrict__ xr2,
    const float* __restrict__ We, const float* __restrict__ att,
    const float* __restrict__ ew_sum, float invE, int E, int n,
    float* __restrict__ agg, float* __restrict__ ssum) {
    long idx = (long)blockIdx.x * blockDim.x + threadIdx.x;
    int e = (int)(idx >> 6);
    int lane = (int)(idx & 63);
    if (e >= E + n) return;
    int ff = *flagf, fi = *flagi;
    int s, d;
    float w;
    if (e < E) {
        s = geti(eix, e, fi);
        d = geti(eix, E + e, fi);
        w = ff ? ((const float*)ewp)[e] : bf2f(((const bf16*)ewp)[e]);
    } else {
        s = d = e - E;
        w = ew_sum[0] * invE;
    }
    const __hip_bfloat162* L = (const __hip_bfloat162*)xl2;
    const __hip_bfloat162* R = (const __hip_bfloat162*)xr2;
    __hip_bfloat162 xlb = L[(long)s * 64 + lane];
    __hip_bfloat162 xrb = R[(long)d * 64 + lane];
    float xlx = bf2f(xlb.x), xly = bf2f(xlb.y);
    int c0 = 2 * lane, c1 = c0 + 1;
    float mx = xlx + bf2f(xrb.x) + w * We[c0];
    float my = xly + bf2f(xrb.y) + w * We[c1];
    mx = mx >= 0.f ? mx : 0.2f * mx;
    my = my >= 0.f ? my : 0.2f * my;
    float p = mx * att[c0] + my * att[c1];
    for (int o = 1; o < 64; o <<= 1) p += __shfl_xor(p, o, 64);
    float ev = __expf(p);
    atomicAdd(&agg[(long)d * D + c0], ev * xlx);
    atomicAdd(&agg[(long)d * D + c1], ev * xly);
    if (lane == 0) atomicAdd(&ssum[d], ev);
}

// ---------- K7: layer-2 epilogue -> out (dtype follows flagf). h1 aliases out. ----------
__global__ void __launch_bounds__(256) k_post2(
    const float* __restrict__ agg, const float* __restrict__ ssum,
    const void* h1, const int* __restrict__ flagf, const float* __restrict__ bias,
    const float* __restrict__ g, const float* __restrict__ be,
    int n, void* out) {
    int v = (int)(((long)blockIdx.x * blockDim.x + threadIdx.x) >> 6);
    int lane = threadIdx.x & 63;
    if (v >= n) return;
    int ff = *flagf;
    int c0 = 2 * lane, c1 = c0 + 1;
    float resx, resy;
    if (ff) {
        float2 rb = ((const float2*)h1)[(long)v * 64 + lane];
        resx = rb.x; resy = rb.y;
    } else {
        __hip_bfloat162 rb = ((const __hip_bfloat162*)h1)[(long)v * 64 + lane];
        resx = bf2f(rb.x); resy = bf2f(rb.y);
    }
    float inv = 1.f / ssum[v];
    float vx = agg[(long)v * D + c0] * inv + bias[c0] + resx;
    float vy = agg[(long)v * D + c1] * inv + bias[c1] + resy;
    float s1 = vx + vy;
    for (int o = 1; o < 64; o <<= 1) s1 += __shfl_xor(s1, o, 64);
    float mu = s1 * (1.f / 128.f);
    float dx = vx - mu, dy = vy - mu;
    float s2 = dx * dx + dy * dy;
    for (int o = 1; o < 64; o <<= 1) s2 += __shfl_xor(s2, o, 64);
    float rstd = rsqrtf(s2 * (1.f / 128.f) + 1e-5f);
    float ox = dx * rstd * g[c0] + be[c0];
    float oy = dy * rstd * g[c1] + be[c1];
    if (ff) {
        ((float2*)out)[(long)v * 64 + lane] = make_float2(ox, oy);
    } else {
        __hip_bfloat162 ob;
        ob.x = __float2bfloat16(ox);
        ob.y = __float2bfloat16(oy);
        ((__hip_bfloat162*)out)[(long)v * 64 + lane] = ob;
    }
}

extern "C" void kernel_launch(void* const* d_in, const int* in_sizes, int n_in,
                              void* d_out, int out_size, void* d_ws, size_t ws_size,
                              hipStream_t stream) {
    const int n = in_sizes[0];
    const int E = in_sizes[1] / 2;
    const int* nid = (const int*)d_in[0];
    const int* eix = (const int*)d_in[1];
    const void* ew = d_in[2];

    char* base = (char*)d_ws;
    size_t off = 0;
    auto alloc = [&](size_t bytes) -> char* {
        size_t o = (off + 15) & ~(size_t)15;
        off = o + bytes;
        return base + o;
    };
    // ws total ~= 52 MB (proven intact in R4: identical output to 30 MB layout)
    int*   flagf  = (int*)alloc(4);
    int*   flagi  = (int*)alloc(4);
    float* ew_sum = (float*)alloc(4);
    float* EWl    = (float*)alloc((size_t)D * D * 4);
    float* EWr    = (float*)alloc((size_t)D * D * 4);
    float* agg    = (float*)alloc((size_t)n * D * 4);   // 25.6 MB
    float* ssum   = (float*)alloc((size_t)n * 4);       // contiguous with agg (zero together)
    bf16*  xl2    = (bf16*)alloc((size_t)n * D * 2);    // 12.8 MB
    bf16*  xr2    = (bf16*)alloc((size_t)n * D * 2);    // 12.8 MB

    CvArgs cv;
    float* P[NCV];
    for (int i = 0; i < NCV; ++i) {
        int sz = in_sizes[3 + i];
        P[i] = (float*)alloc((size_t)sz * 4);
        cv.s[i] = d_in[3 + i];
        cv.d[i] = P[i];
        cv.n[i] = sz;
    }
    float* emb_f = P[0];
    float* w1l = P[1], *b1l = P[2], *w1r = P[3], *b1r = P[4];
    float* w1e = P[5], *att1 = P[6], *bias1 = P[7], *g1 = P[8], *be1 = P[9];
    float* w2l = P[10], *b2l = P[11], *w2r = P[12], *b2r = P[13];
    float* w2e = P[14], *att2 = P[15], *bias2 = P[16], *g2 = P[17], *be2 = P[18];

    void* h1 = d_out;  // h1 lives in d_out (same dtype as final output in both worlds)

    const float invE = 1.0f / (float)E;
    const int zcnt = n * D + n;
    const long ethreads = (long)(E + n) * 64;
    const int eblocks = (int)((ethreads + 255) / 256);

    k_detect_f<<<1, 256, 0, stream>>>(d_in[3], in_sizes[3], flagf, ew_sum);
    k_detect_i<<<1, 256, 0, stream>>>(eix, flagi);
    k_convert<<<NCV, 256, 0, stream>>>(cv, flagf);
    k_ew_sum<<<256, 256, 0, stream>>>(ew, E, flagf, ew_sum);
    k_tables<<<D, D, 0, stream>>>(emb_f, w1l, b1l, w1r, b1r, EWl, EWr);

    // ---- layer 1 ----
    k_zerof<<<2048, 256, 0, stream>>>(agg, zcnt);
    k_edge1<<<eblocks, 256, 0, stream>>>(nid, eix, ew, flagf, flagi, EWl, EWr,
                                         w1e, att1, ew_sum, invE, E, n, agg, ssum);
    k_post1<<<(n + 3) / 4, 256, 0, stream>>>(nid, flagi, flagf, agg, ssum, emb_f,
                                             bias1, g1, be1, n, h1);
    // ---- layer 2 ----
    k_gemm2<<<(n + 15) / 16, 128, 0, stream>>>(h1, flagf, w2l, b2l, w2r, b2r, n, xl2, xr2);
    k_zerof<<<2048, 256, 0, stream>>>(agg, zcnt);
    k_edge2<<<eblocks, 256, 0, stream>>>(eix, ew, flagf, flagi, xl2, xr2,
                                         w2e, att2, ew_sum, invE, E, n, agg, ssum);
    k_post2<<<(n + 3) / 4, 256, 0, stream>>>(agg, ssum, h1, flagf, bias2, g2, be2, n, d_out);
}

// Round 6
// 545.533 us; speedup vs baseline: 3.4784x; 3.4784x over previous
//
#include <hip/hip_runtime.h>
#include <hip/hip_bf16.h>

#define D 128
typedef __hip_bfloat16 bf16;

static __device__ __forceinline__ float bf2f(bf16 v) { return __bfloat162float(v); }
// int access adapting to int32 (f64=0) or int64 little-endian (f64=1) storage
static __device__ __forceinline__ int geti(const int* p, int k, int f64) {
    return f64 ? p[2 * k] : p[k];
}
static __device__ __forceinline__ unsigned short f_to_u16bf(float f) {
    unsigned u = __float_as_uint(f);
    return (unsigned short)((u + 0x7FFFu + ((u >> 16) & 1u)) >> 16);  // RNE
}

// ---------- K0a: float-storage detector (bf16 vs f32) + zero ew_sum ----------
__global__ void k_detect_f(const void* __restrict__ embp, int m,
                           int* __restrict__ flagf, float* __restrict__ ew_sum) {
    int bad = 0;
    const bf16* e = (const bf16*)embp;
    for (int i = threadIdx.x; i < m; i += 256) {
        float f = bf2f(e[i]);
        if (!(fabsf(f) <= 100.f)) bad = 1;
    }
    __shared__ int sh;
    if (threadIdx.x == 0) { sh = 0; *ew_sum = 0.f; }
    __syncthreads();
    if (bad) atomicOr(&sh, 1);
    __syncthreads();
    if (threadIdx.x == 0) *flagf = sh;  // 1 = f32 storage, 0 = bf16 storage
}

// ---------- K0b: int-storage detector (int32 vs int64) ----------
__global__ void k_detect_i(const int* __restrict__ eix, int* __restrict__ flagi) {
    int nz = 0;
    for (int k = threadIdx.x; k < 4096; k += 256)
        if (eix[2 * k + 1] != 0) nz = 1;
    __shared__ int sh;
    if (threadIdx.x == 0) sh = 0;
    __syncthreads();
    if (nz) atomicOr(&sh, 1);
    __syncthreads();
    if (threadIdx.x == 0) *flagi = sh ? 0 : 1;  // 1 = int64 storage
}

// ---------- K0c: canonicalize the 19 float param tensors to f32; zero counts ----------
#define NCV 19
struct CvArgs { const void* s[NCV]; float* d[NCV]; int n[NCV]; };
__global__ void k_convert(CvArgs a, const int* __restrict__ flagf) {
    int f = *flagf;
    int b = blockIdx.x;
    const void* sp = a.s[b];
    float* dp = a.d[b];
    int m = a.n[b];
    if (f) {
        const float* s = (const float*)sp;
        for (int i = threadIdx.x; i < m; i += blockDim.x) dp[i] = s[i];
    } else {
        const bf16* s = (const bf16*)sp;
        for (int i = threadIdx.x; i < m; i += blockDim.x) dp[i] = bf2f(s[i]);
    }
}

__global__ void k_zeroi(int* __restrict__ p, int cnt) {
    int i = blockIdx.x * blockDim.x + threadIdx.x;
    if (i < cnt) p[i] = 0;
}

// ---------- K1: sum of edge weights ----------
__global__ void k_ew_sum(const void* __restrict__ wp, int E, const int* __restrict__ flagf,
                         float* __restrict__ out) {
    int f = *flagf;
    float s = 0.f;
    for (int i = blockIdx.x * blockDim.x + threadIdx.x; i < E; i += gridDim.x * blockDim.x)
        s += f ? ((const float*)wp)[i] : bf2f(((const bf16*)wp)[i]);
    for (int o = 32; o > 0; o >>= 1) s += __shfl_down(s, o, 64);
    __shared__ float ls[4];
    if ((threadIdx.x & 63) == 0) ls[threadIdx.x >> 6] = s;
    __syncthreads();
    if (threadIdx.x == 0) atomicAdd(out, ls[0] + ls[1] + ls[2] + ls[3]);
}

// ---------- K2: layer-1 vocab tables EWl = emb@W1l + b1l, EWr = emb@W1r + b1r ----------
__global__ void k_tables(const float* __restrict__ emb,
                         const float* __restrict__ Wl, const float* __restrict__ bl,
                         const float* __restrict__ Wr, const float* __restrict__ br,
                         float* __restrict__ EWl, float* __restrict__ EWr) {
    int r = blockIdx.x, c = threadIdx.x;
    __shared__ float er[D];
    er[c] = emb[r * D + c];
    __syncthreads();
    float al = bl[c], ar = br[c];
    for (int k = 0; k < D; ++k) {
        float e = er[k];
        al += e * Wl[k * D + c];
        ar += e * Wr[k * D + c];
    }
    EWl[r * D + c] = al;
    EWr[r * D + c] = ar;
}

// ---------- K3: histogram of dst ----------
__global__ void k_hist(const int* __restrict__ eix, int E, const int* __restrict__ flagi,
                       int* __restrict__ counts) {
    int fi = *flagi;
    for (int e = blockIdx.x * blockDim.x + threadIdx.x; e < E; e += gridDim.x * blockDim.x)
        atomicAdd(&counts[geti(eix, E + e, fi)], 1);
}

// ---------- K4: two-level exclusive scan ----------
__global__ void k_scan1(const int* __restrict__ counts, int n, int* __restrict__ offs,
                        int* __restrict__ bsum) {
    __shared__ int s[256];
    int t = threadIdx.x;
    int i = blockIdx.x * 256 + t;
    int v = (i < n) ? counts[i] : 0;
    s[t] = v;
    __syncthreads();
    for (int o = 1; o < 256; o <<= 1) {
        int x = (t >= o) ? s[t - o] : 0;
        __syncthreads();
        s[t] += x;
        __syncthreads();
    }
    if (i < n) offs[i] = s[t] - v;
    if (t == 255) bsum[blockIdx.x] = s[255];
}

__global__ void k_scan2(int* __restrict__ bsum, int nb) {
    __shared__ int s[256];
    int t = threadIdx.x;
    int v = (t < nb) ? bsum[t] : 0;
    s[t] = v;
    __syncthreads();
    for (int o = 1; o < 256; o <<= 1) {
        int x = (t >= o) ? s[t - o] : 0;
        __syncthreads();
        s[t] += x;
        __syncthreads();
    }
    if (t < nb) bsum[t] = s[t] - v;
}

__global__ void k_scan3(int* __restrict__ offs, const int* __restrict__ bsum, int n, int E,
                        int* __restrict__ cursor) {
    int i = blockIdx.x * blockDim.x + threadIdx.x;
    if (i < n) {
        int o = offs[i] + bsum[i >> 8];
        offs[i] = o;
        cursor[i] = o;
    }
    if (i == 0) offs[n] = E;
}

// ---------- K5: scatter edges into packed CSR (src low16, bf16 wgt high16) ----------
__global__ void k_scatter(const int* __restrict__ eix, const void* __restrict__ ewp, int E,
                          const int* __restrict__ flagf, const int* __restrict__ flagi,
                          int* __restrict__ cursor, unsigned* __restrict__ csr) {
    int ff = *flagf, fi = *flagi;
    for (int e = blockIdx.x * blockDim.x + threadIdx.x; e < E; e += gridDim.x * blockDim.x) {
        int d = geti(eix, E + e, fi);
        int pos = atomicAdd(&cursor[d], 1);
        unsigned short wb;
        if (ff) wb = f_to_u16bf(((const float*)ewp)[e]);
        else    wb = ((const unsigned short*)ewp)[e];
        csr[pos] = (unsigned)(geti(eix, e, fi) & 0xFFFF) | ((unsigned)wb << 16);
    }
}

// ---------- K6: layer-1 per-node fused agg + residual + LN -> h1 (in d_out) ----------
// one wave per node, no atomics; EWl/EWr are 64 KB L1-resident tables
__global__ void __launch_bounds__(256) k_agg1(
    const int* __restrict__ nid, const int* __restrict__ offs,
    const unsigned* __restrict__ csr,
    const float* __restrict__ EWl, const float* __restrict__ EWr,
    const float* __restrict__ emb,
    const float* __restrict__ We, const float* __restrict__ att,
    const float* __restrict__ bias, const float* __restrict__ g, const float* __restrict__ be,
    const float* __restrict__ ew_sum, float invE, int n,
    const int* __restrict__ flagf, const int* __restrict__ flagi,
    void* __restrict__ h1) {
    int v = (int)(((long)blockIdx.x * blockDim.x + threadIdx.x) >> 6);
    int lane = threadIdx.x & 63;
    if (v >= n) return;
    int fi = *flagi;
    int tv = geti(nid, v, fi);
    const float2* L = (const float2*)EWl;
    const float2* R = (const float2*)EWr;
    float2 xr = R[tv * 64 + lane];
    int c0 = 2 * lane, c1 = c0 + 1;
    float wex = We[c0], wey = We[c1];
    float ax = att[c0], ay = att[c1];
    float wmean = ew_sum[0] * invE;

    float den = 0.f, accx = 0.f, accy = 0.f;
    int e0 = offs[v], e1 = offs[v + 1];
    for (int e = e0 - 1; e < e1; ++e) {
        int s;
        float wgt;
        if (e < e0) { s = v; wgt = wmean; }  // self loop
        else {
            unsigned pk = csr[e];
            s = (int)(pk & 0xFFFFu);
            wgt = __uint_as_float(pk & 0xFFFF0000u);
        }
        int ts = geti(nid, s, fi);
        float2 xl = L[ts * 64 + lane];
        float mx = xl.x + xr.x + wgt * wex;
        float my = xl.y + xr.y + wgt * wey;
        mx = mx >= 0.f ? mx : 0.2f * mx;
        my = my >= 0.f ? my : 0.2f * my;
        float p = mx * ax + my * ay;
        for (int o = 1; o < 64; o <<= 1) p += __shfl_xor(p, o, 64);
        float ev = __expf(p);
        den += ev;
        accx += ev * xl.x;
        accy += ev * xl.y;
    }
    float inv = 1.f / den;
    float vx = accx * inv + bias[c0] + emb[tv * D + c0];
    float vy = accy * inv + bias[c1] + emb[tv * D + c1];
    float s1 = vx + vy;
    for (int o = 1; o < 64; o <<= 1) s1 += __shfl_xor(s1, o, 64);
    float mu = s1 * (1.f / 128.f);
    float dx = vx - mu, dy = vy - mu;
    float s2 = dx * dx + dy * dy;
    for (int o = 1; o < 64; o <<= 1) s2 += __shfl_xor(s2, o, 64);
    float rstd = rsqrtf(s2 * (1.f / 128.f) + 1e-5f);
    float ox = dx * rstd * g[c0] + be[c0];
    float oy = dy * rstd * g[c1] + be[c1];
    if (*flagf) {
        ((float2*)h1)[(long)v * 64 + lane] = make_float2(ox, oy);
    } else {
        __hip_bfloat162 hb;
        hb.x = __float2bfloat16(ox);
        hb.y = __float2bfloat16(oy);
        ((__hip_bfloat162*)h1)[(long)v * 64 + lane] = hb;
    }
}

// ---------- K7: layer-2 GEMMs xl2 = h1@W2l + b2l, xr2 = h1@W2r + b2r (bf16 out) ----------
__global__ void __launch_bounds__(128) k_gemm2(
    const void* __restrict__ h1, const int* __restrict__ flagf,
    const float* __restrict__ Wl, const float* __restrict__ bl,
    const float* __restrict__ Wr, const float* __restrict__ br, int n,
    bf16* __restrict__ xl2, bf16* __restrict__ xr2) {
    const int BN = 16;
    __shared__ float xs[BN][D];
    int v0 = blockIdx.x * BN;
    int t = threadIdx.x;
    int ff = *flagf;
    for (int i = t; i < BN * D; i += 128) {
        int r = i >> 7, c = i & 127;
        int v = v0 + r;
        float x = 0.f;
        if (v < n)
            x = ff ? ((const float*)h1)[(long)v * D + c]
                   : bf2f(((const bf16*)h1)[(long)v * D + c]);
        xs[r][c] = x;
    }
    __syncthreads();
    int c = t;
    float accl[BN], accr[BN];
    float blc = bl[c], brc = br[c];
#pragma unroll
    for (int r = 0; r < BN; ++r) { accl[r] = blc; accr[r] = brc; }
    for (int k = 0; k < D; ++k) {
        float wl = Wl[k * D + c];
        float wr = Wr[k * D + c];
#pragma unroll
        for (int r = 0; r < BN; ++r) {
            float s = xs[r][k];
            accl[r] += s * wl;
            accr[r] += s * wr;
        }
    }
    for (int r = 0; r < BN; ++r) {
        int v = v0 + r;
        if (v < n) {
            xl2[(long)v * D + c] = __float2bfloat16(accl[r]);
            xr2[(long)v * D + c] = __float2bfloat16(accr[r]);
        }
    }
}

// ---------- K8: layer-2 per-node fused agg + residual + LN -> out. h1 aliases out. ----------
__global__ void __launch_bounds__(256) k_agg2(
    const int* __restrict__ offs, const unsigned* __restrict__ csr,
    const bf16* __restrict__ xl2, const bf16* __restrict__ xr2,
    const void* h1,
    const float* __restrict__ We, const float* __restrict__ att,
    const float* __restrict__ bias, const float* __restrict__ g, const float* __restrict__ be,
    const float* __restrict__ ew_sum, float invE, int n,
    const int* __restrict__ flagf, void* out) {
    int v = (int)(((long)blockIdx.x * blockDim.x + threadIdx.x) >> 6);
    int lane = threadIdx.x & 63;
    if (v >= n) return;
    int ff = *flagf;
    int c0 = 2 * lane, c1 = c0 + 1;
    // residual read early (h1 aliases out; own row only)
    float resx, resy;
    if (ff) {
        float2 rb = ((const float2*)h1)[(long)v * 64 + lane];
        resx = rb.x; resy = rb.y;
    } else {
        __hip_bfloat162 rb = ((const __hip_bfloat162*)h1)[(long)v * 64 + lane];
        resx = bf2f(rb.x); resy = bf2f(rb.y);
    }
    const __hip_bfloat162* L = (const __hip_bfloat162*)xl2;
    const __hip_bfloat162* R = (const __hip_bfloat162*)xr2;
    __hip_bfloat162 xrb = R[(long)v * 64 + lane];
    float xrx = bf2f(xrb.x), xry = bf2f(xrb.y);
    float wex = We[c0], wey = We[c1];
    float ax = att[c0], ay = att[c1];
    float wmean = ew_sum[0] * invE;

    float den = 0.f, accx = 0.f, accy = 0.f;
    int e0 = offs[v], e1 = offs[v + 1];
    for (int e = e0 - 1; e < e1; ++e) {
        int s;
        float wgt;
        if (e < e0) { s = v; wgt = wmean; }
        else {
            unsigned pk = csr[e];
            s = (int)(pk & 0xFFFFu);
            wgt = __uint_as_float(pk & 0xFFFF0000u);
        }
        __hip_bfloat162 xlb = L[(long)s * 64 + lane];
        float xlx = bf2f(xlb.x), xly = bf2f(xlb.y);
        float mx = xlx + xrx + wgt * wex;
        float my = xly + xry + wgt * wey;
        mx = mx >= 0.f ? mx : 0.2f * mx;
        my = my >= 0.f ? my : 0.2f * my;
        float p = mx * ax + my * ay;
        for (int o = 1; o < 64; o <<= 1) p += __shfl_xor(p, o, 64);
        float ev = __expf(p);
        den += ev;
        accx += ev * xlx;
        accy += ev * xly;
    }
    float inv = 1.f / den;
    float vx = accx * inv + bias[c0] + resx;
    float vy = accy * inv + bias[c1] + resy;
    float s1 = vx + vy;
    for (int o = 1; o < 64; o <<= 1) s1 += __shfl_xor(s1, o, 64);
    float mu = s1 * (1.f / 128.f);
    float dx = vx - mu, dy = vy - mu;
    float s2 = dx * dx + dy * dy;
    for (int o = 1; o < 64; o <<= 1) s2 += __shfl_xor(s2, o, 64);
    float rstd = rsqrtf(s2 * (1.f / 128.f) + 1e-5f);
    float ox = dx * rstd * g[c0] + be[c0];
    float oy = dy * rstd * g[c1] + be[c1];
    if (ff) {
        ((float2*)out)[(long)v * 64 + lane] = make_float2(ox, oy);
    } else {
        __hip_bfloat162 ob;
        ob.x = __float2bfloat16(ox);
        ob.y = __float2bfloat16(oy);
        ((__hip_bfloat162*)out)[(long)v * 64 + lane] = ob;
    }
}

extern "C" void kernel_launch(void* const* d_in, const int* in_sizes, int n_in,
                              void* d_out, int out_size, void* d_ws, size_t ws_size,
                              hipStream_t stream) {
    const int n = in_sizes[0];
    const int E = in_sizes[1] / 2;
    const int* nid = (const int*)d_in[0];
    const int* eix = (const int*)d_in[1];
    const void* ew = d_in[2];

    char* base = (char*)d_ws;
    size_t off = 0;
    auto alloc = [&](size_t bytes) -> char* {
        size_t o = (off + 15) & ~(size_t)15;
        off = o + bytes;
        return base + o;
    };
    // ws total ~= 30 MB
    int*   flagf  = (int*)alloc(4);
    int*   flagi  = (int*)alloc(4);
    float* ew_sum = (float*)alloc(4);
    float* EWl    = (float*)alloc((size_t)D * D * 4);
    float* EWr    = (float*)alloc((size_t)D * D * 4);
    int*   offs     = (int*)alloc((size_t)(n + 1) * 4);
    int*   countcur = (int*)alloc((size_t)n * 4);  // counts, then cursor
    int*   bsum     = (int*)alloc(256 * 4);
    unsigned* csr   = (unsigned*)alloc((size_t)E * 4);   // 3.2 MB
    bf16*  xl2    = (bf16*)alloc((size_t)n * D * 2);     // 12.8 MB
    bf16*  xr2    = (bf16*)alloc((size_t)n * D * 2);     // 12.8 MB

    CvArgs cv;
    float* P[NCV];
    for (int i = 0; i < NCV; ++i) {
        int sz = in_sizes[3 + i];
        P[i] = (float*)alloc((size_t)sz * 4);
        cv.s[i] = d_in[3 + i];
        cv.d[i] = P[i];
        cv.n[i] = sz;
    }
    float* emb_f = P[0];
    float* w1l = P[1], *b1l = P[2], *w1r = P[3], *b1r = P[4];
    float* w1e = P[5], *att1 = P[6], *bias1 = P[7], *g1 = P[8], *be1 = P[9];
    float* w2l = P[10], *b2l = P[11], *w2r = P[12], *b2r = P[13];
    float* w2e = P[14], *att2 = P[15], *bias2 = P[16], *g2 = P[17], *be2 = P[18];

    void* h1 = d_out;  // h1 lives in d_out (same dtype as final output either way)

    const float invE = 1.0f / (float)E;
    const int nb = (n + 255) / 256;

    k_detect_f<<<1, 256, 0, stream>>>(d_in[3], in_sizes[3], flagf, ew_sum);
    k_detect_i<<<1, 256, 0, stream>>>(eix, flagi);
    k_convert<<<NCV, 256, 0, stream>>>(cv, flagf);
    k_zeroi<<<nb, 256, 0, stream>>>(countcur, n);
    k_ew_sum<<<256, 256, 0, stream>>>(ew, E, flagf, ew_sum);
    k_tables<<<D, D, 0, stream>>>(emb_f, w1l, b1l, w1r, b1r, EWl, EWr);

    // ---- CSR build ----
    k_hist<<<512, 256, 0, stream>>>(eix, E, flagi, countcur);
    k_scan1<<<nb, 256, 0, stream>>>(countcur, n, offs, bsum);
    k_scan2<<<1, 256, 0, stream>>>(bsum, nb);
    k_scan3<<<nb, 256, 0, stream>>>(offs, bsum, n, E, countcur);
    k_scatter<<<512, 256, 0, stream>>>(eix, ew, E, flagf, flagi, countcur, csr);

    // ---- layer 1 (fused agg + LN) ----
    k_agg1<<<(n + 3) / 4, 256, 0, stream>>>(nid, offs, csr, EWl, EWr, emb_f,
                                            w1e, att1, bias1, g1, be1,
                                            ew_sum, invE, n, flagf, flagi, h1);
    // ---- layer 2 ----
    k_gemm2<<<(n + 15) / 16, 128, 0, stream>>>(h1, flagf, w2l, b2l, w2r, b2r, n, xl2, xr2);
    k_agg2<<<(n + 3) / 4, 256, 0, stream>>>(offs, csr, xl2, xr2, h1,
                                            w2e, att2, bias2, g2, be2,
                                            ew_sum, invE, n, flagf, d_out);
}

// Round 7
// 496.998 us; speedup vs baseline: 3.8181x; 1.0977x over previous
//
#include <hip/hip_runtime.h>
#include <hip/hip_bf16.h>

#define D 128
typedef __hip_bfloat16 bf16;

static __device__ __forceinline__ float bf2f(bf16 v) { return __bfloat162float(v); }
// int access adapting to int32 (f64=0) or int64 little-endian (f64=1) storage
static __device__ __forceinline__ int geti(const int* p, int k, int f64) {
    return f64 ? p[2 * k] : p[k];
}
static __device__ __forceinline__ unsigned short f_to_u16bf(float f) {
    unsigned u = __float_as_uint(f);
    return (unsigned short)((u + 0x7FFFu + ((u >> 16) & 1u)) >> 16);  // RNE
}

// ---------- K0a: float-storage detector (bf16 vs f32) + zero ew_sum ----------
__global__ void k_detect_f(const void* __restrict__ embp, int m,
                           int* __restrict__ flagf, float* __restrict__ ew_sum) {
    int bad = 0;
    const bf16* e = (const bf16*)embp;
    for (int i = threadIdx.x; i < m; i += 256) {
        float f = bf2f(e[i]);
        if (!(fabsf(f) <= 100.f)) bad = 1;
    }
    __shared__ int sh;
    if (threadIdx.x == 0) { sh = 0; *ew_sum = 0.f; }
    __syncthreads();
    if (bad) atomicOr(&sh, 1);
    __syncthreads();
    if (threadIdx.x == 0) *flagf = sh;  // 1 = f32 storage, 0 = bf16 storage
}

// ---------- K0b: int-storage detector (int32 vs int64) ----------
__global__ void k_detect_i(const int* __restrict__ eix, int* __restrict__ flagi) {
    int nz = 0;
    for (int k = threadIdx.x; k < 4096; k += 256)
        if (eix[2 * k + 1] != 0) nz = 1;
    __shared__ int sh;
    if (threadIdx.x == 0) sh = 0;
    __syncthreads();
    if (nz) atomicOr(&sh, 1);
    __syncthreads();
    if (threadIdx.x == 0) *flagi = sh ? 0 : 1;  // 1 = int64 storage
}

// ---------- K0c: canonicalize the 19 float param tensors to f32 ----------
#define NCV 19
struct CvArgs { const void* s[NCV]; float* d[NCV]; int n[NCV]; };
__global__ void k_convert(CvArgs a, const int* __restrict__ flagf) {
    int f = *flagf;
    int b = blockIdx.x;
    const void* sp = a.s[b];
    float* dp = a.d[b];
    int m = a.n[b];
    if (f) {
        const float* s = (const float*)sp;
        for (int i = threadIdx.x; i < m; i += blockDim.x) dp[i] = s[i];
    } else {
        const bf16* s = (const bf16*)sp;
        for (int i = threadIdx.x; i < m; i += blockDim.x) dp[i] = bf2f(s[i]);
    }
}

__global__ void k_zeroi(int* __restrict__ p, int cnt) {
    int i = blockIdx.x * blockDim.x + threadIdx.x;
    if (i < cnt) p[i] = 0;
}

// ---------- K1: sum of edge weights ----------
__global__ void k_ew_sum(const void* __restrict__ wp, int E, const int* __restrict__ flagf,
                         float* __restrict__ out) {
    int f = *flagf;
    float s = 0.f;
    for (int i = blockIdx.x * blockDim.x + threadIdx.x; i < E; i += gridDim.x * blockDim.x)
        s += f ? ((const float*)wp)[i] : bf2f(((const bf16*)wp)[i]);
    for (int o = 32; o > 0; o >>= 1) s += __shfl_down(s, o, 64);
    __shared__ float ls[4];
    if ((threadIdx.x & 63) == 0) ls[threadIdx.x >> 6] = s;
    __syncthreads();
    if (threadIdx.x == 0) atomicAdd(out, ls[0] + ls[1] + ls[2] + ls[3]);
}

// ---------- K2: layer-1 vocab tables EWl = emb@W1l + b1l, EWr = emb@W1r + b1r ----------
__global__ void k_tables(const float* __restrict__ emb,
                         const float* __restrict__ Wl, const float* __restrict__ bl,
                         const float* __restrict__ Wr, const float* __restrict__ br,
                         float* __restrict__ EWl, float* __restrict__ EWr) {
    int r = blockIdx.x, c = threadIdx.x;
    __shared__ float er[D];
    er[c] = emb[r * D + c];
    __syncthreads();
    float al = bl[c], ar = br[c];
    for (int k = 0; k < D; ++k) {
        float e = er[k];
        al += e * Wl[k * D + c];
        ar += e * Wr[k * D + c];
    }
    EWl[r * D + c] = al;
    EWr[r * D + c] = ar;
}

// ---------- K3: histogram of dst ----------
__global__ void k_hist(const int* __restrict__ eix, int E, const int* __restrict__ flagi,
                       int* __restrict__ counts) {
    int fi = *flagi;
    for (int e = blockIdx.x * blockDim.x + threadIdx.x; e < E; e += gridDim.x * blockDim.x)
        atomicAdd(&counts[geti(eix, E + e, fi)], 1);
}

// ---------- K4: two-level exclusive scan ----------
__global__ void k_scan1(const int* __restrict__ counts, int n, int* __restrict__ offs,
                        int* __restrict__ bsum) {
    __shared__ int s[256];
    int t = threadIdx.x;
    int i = blockIdx.x * 256 + t;
    int v = (i < n) ? counts[i] : 0;
    s[t] = v;
    __syncthreads();
    for (int o = 1; o < 256; o <<= 1) {
        int x = (t >= o) ? s[t - o] : 0;
        __syncthreads();
        s[t] += x;
        __syncthreads();
    }
    if (i < n) offs[i] = s[t] - v;
    if (t == 255) bsum[blockIdx.x] = s[255];
}

__global__ void k_scan2(int* __restrict__ bsum, int nb) {
    __shared__ int s[256];
    int t = threadIdx.x;
    int v = (t < nb) ? bsum[t] : 0;
    s[t] = v;
    __syncthreads();
    for (int o = 1; o < 256; o <<= 1) {
        int x = (t >= o) ? s[t - o] : 0;
        __syncthreads();
        s[t] += x;
        __syncthreads();
    }
    if (t < nb) bsum[t] = s[t] - v;
}

__global__ void k_scan3(int* __restrict__ offs, const int* __restrict__ bsum, int n, int E,
                        int* __restrict__ cursor) {
    int i = blockIdx.x * blockDim.x + threadIdx.x;
    if (i < n) {
        int o = offs[i] + bsum[i >> 8];
        offs[i] = o;
        cursor[i] = o;
    }
    if (i == 0) offs[n] = E;
}

// ---------- K5: scatter edges into packed CSR (src low16, bf16 wgt high16) ----------
__global__ void k_scatter(const int* __restrict__ eix, const void* __restrict__ ewp, int E,
                          const int* __restrict__ flagf, const int* __restrict__ flagi,
                          int* __restrict__ cursor, unsigned* __restrict__ csr) {
    int ff = *flagf, fi = *flagi;
    for (int e = blockIdx.x * blockDim.x + threadIdx.x; e < E; e += gridDim.x * blockDim.x) {
        int d = geti(eix, E + e, fi);
        int pos = atomicAdd(&cursor[d], 1);
        unsigned short wb;
        if (ff) wb = f_to_u16bf(((const float*)ewp)[e]);
        else    wb = ((const unsigned short*)ewp)[e];
        csr[pos] = (unsigned)(geti(eix, e, fi) & 0xFFFF) | ((unsigned)wb << 16);
    }
}

// ---------- K6: layer-1 per-node fused agg + residual + LN -> h1 (in d_out) ----------
// one wave per node; edge loop unrolled x4 (4 independent shfl chains + gathers in flight)
__global__ void __launch_bounds__(256) k_agg1(
    const int* __restrict__ nid, const int* __restrict__ offs,
    const unsigned* __restrict__ csr,
    const float* __restrict__ EWl, const float* __restrict__ EWr,
    const float* __restrict__ emb,
    const float* __restrict__ We, const float* __restrict__ att,
    const float* __restrict__ bias, const float* __restrict__ g, const float* __restrict__ be,
    const float* __restrict__ ew_sum, float invE, int n,
    const int* __restrict__ flagf, const int* __restrict__ flagi,
    void* __restrict__ h1) {
    int v = (int)(((long)blockIdx.x * blockDim.x + threadIdx.x) >> 6);
    int lane = threadIdx.x & 63;
    if (v >= n) return;
    int fi = *flagi;
    int tv = geti(nid, v, fi);
    const float2* L = (const float2*)EWl;
    const float2* R = (const float2*)EWr;
    float2 xr = R[tv * 64 + lane];
    int c0 = 2 * lane, c1 = c0 + 1;
    float wex = We[c0], wey = We[c1];
    float ax = att[c0], ay = att[c1];
    float wmean = ew_sum[0] * invE;

    float den = 0.f, accx = 0.f, accy = 0.f;
    int e0 = offs[v];
    int cnt = offs[v + 1] - e0 + 1;  // +1 for the self loop (i==0)
    for (int base = 0; base < cnt; base += 4) {
        float p[4], lx[4], ly[4];
#pragma unroll
        for (int j = 0; j < 4; ++j) {
            int i = base + j;
            int s = v;
            float wgt = wmean;
            if (i > 0 && i < cnt) {
                unsigned pk = csr[e0 + i - 1];
                s = (int)(pk & 0xFFFFu);
                wgt = __uint_as_float(pk & 0xFFFF0000u);
            }
            int ts = geti(nid, s, fi);
            float2 xl = L[ts * 64 + lane];
            lx[j] = xl.x;
            ly[j] = xl.y;
            float mx = xl.x + xr.x + wgt * wex;
            float my = xl.y + xr.y + wgt * wey;
            mx = fmaxf(mx, 0.f) + 0.2f * fminf(mx, 0.f);
            my = fmaxf(my, 0.f) + 0.2f * fminf(my, 0.f);
            p[j] = mx * ax + my * ay;
        }
#pragma unroll
        for (int o = 1; o < 64; o <<= 1) {
#pragma unroll
            for (int j = 0; j < 4; ++j) p[j] += __shfl_xor(p[j], o, 64);
        }
#pragma unroll
        for (int j = 0; j < 4; ++j) {
            float ev = (base + j < cnt) ? __expf(p[j]) : 0.f;
            den += ev;
            accx += ev * lx[j];
            accy += ev * ly[j];
        }
    }
    float inv = 1.f / den;
    float vx = accx * inv + bias[c0] + emb[tv * D + c0];
    float vy = accy * inv + bias[c1] + emb[tv * D + c1];
    float s1 = vx + vy;
    for (int o = 1; o < 64; o <<= 1) s1 += __shfl_xor(s1, o, 64);
    float mu = s1 * (1.f / 128.f);
    float dx = vx - mu, dy = vy - mu;
    float s2 = dx * dx + dy * dy;
    for (int o = 1; o < 64; o <<= 1) s2 += __shfl_xor(s2, o, 64);
    float rstd = rsqrtf(s2 * (1.f / 128.f) + 1e-5f);
    float ox = dx * rstd * g[c0] + be[c0];
    float oy = dy * rstd * g[c1] + be[c1];
    if (*flagf) {
        ((float2*)h1)[(long)v * 64 + lane] = make_float2(ox, oy);
    } else {
        __hip_bfloat162 hb;
        hb.x = __float2bfloat16(ox);
        hb.y = __float2bfloat16(oy);
        ((__hip_bfloat162*)h1)[(long)v * 64 + lane] = hb;
    }
}

// ---------- K7: layer-2 GEMMs xl2 = h1@W2l + b2l, xr2 = h1@W2r + b2r (bf16 out) ----------
__global__ void __launch_bounds__(128) k_gemm2(
    const void* __restrict__ h1, const int* __restrict__ flagf,
    const float* __restrict__ Wl, const float* __restrict__ bl,
    const float* __restrict__ Wr, const float* __restrict__ br, int n,
    bf16* __restrict__ xl2, bf16* __restrict__ xr2) {
    const int BN = 16;
    __shared__ float xs[BN][D];
    int v0 = blockIdx.x * BN;
    int t = threadIdx.x;
    int ff = *flagf;
    for (int i = t; i < BN * D; i += 128) {
        int r = i >> 7, c = i & 127;
        int v = v0 + r;
        float x = 0.f;
        if (v < n)
            x = ff ? ((const float*)h1)[(long)v * D + c]
                   : bf2f(((const bf16*)h1)[(long)v * D + c]);
        xs[r][c] = x;
    }
    __syncthreads();
    int c = t;
    float accl[BN], accr[BN];
    float blc = bl[c], brc = br[c];
#pragma unroll
    for (int r = 0; r < BN; ++r) { accl[r] = blc; accr[r] = brc; }
    for (int k = 0; k < D; ++k) {
        float wl = Wl[k * D + c];
        float wr = Wr[k * D + c];
#pragma unroll
        for (int r = 0; r < BN; ++r) {
            float s = xs[r][k];
            accl[r] += s * wl;
            accr[r] += s * wr;
        }
    }
    for (int r = 0; r < BN; ++r) {
        int v = v0 + r;
        if (v < n) {
            xl2[(long)v * D + c] = __float2bfloat16(accl[r]);
            xr2[(long)v * D + c] = __float2bfloat16(accr[r]);
        }
    }
}

// ---------- K8: layer-2 per-node fused agg + residual + LN -> out. h1 aliases out. ----------
__global__ void __launch_bounds__(256) k_agg2(
    const int* __restrict__ offs, const unsigned* __restrict__ csr,
    const bf16* __restrict__ xl2, const bf16* __restrict__ xr2,
    const void* h1,
    const float* __restrict__ We, const float* __restrict__ att,
    const float* __restrict__ bias, const float* __restrict__ g, const float* __restrict__ be,
    const float* __restrict__ ew_sum, float invE, int n,
    const int* __restrict__ flagf, void* out) {
    int v = (int)(((long)blockIdx.x * blockDim.x + threadIdx.x) >> 6);
    int lane = threadIdx.x & 63;
    if (v >= n) return;
    int ff = *flagf;
    int c0 = 2 * lane, c1 = c0 + 1;
    // residual read early (h1 aliases out; own row only)
    float resx, resy;
    if (ff) {
        float2 rb = ((const float2*)h1)[(long)v * 64 + lane];
        resx = rb.x; resy = rb.y;
    } else {
        __hip_bfloat162 rb = ((const __hip_bfloat162*)h1)[(long)v * 64 + lane];
        resx = bf2f(rb.x); resy = bf2f(rb.y);
    }
    const __hip_bfloat162* L = (const __hip_bfloat162*)xl2;
    const __hip_bfloat162* R = (const __hip_bfloat162*)xr2;
    __hip_bfloat162 xrb = R[(long)v * 64 + lane];
    float xrx = bf2f(xrb.x), xry = bf2f(xrb.y);
    float wex = We[c0], wey = We[c1];
    float ax = att[c0], ay = att[c1];
    float wmean = ew_sum[0] * invE;

    float den = 0.f, accx = 0.f, accy = 0.f;
    int e0 = offs[v];
    int cnt = offs[v + 1] - e0 + 1;  // +1 for the self loop (i==0)
    for (int base = 0; base < cnt; base += 4) {
        float p[4], lx[4], ly[4];
#pragma unroll
        for (int j = 0; j < 4; ++j) {
            int i = base + j;
            int s = v;
            float wgt = wmean;
            if (i > 0 && i < cnt) {
                unsigned pk = csr[e0 + i - 1];
                s = (int)(pk & 0xFFFFu);
                wgt = __uint_as_float(pk & 0xFFFF0000u);
            }
            __hip_bfloat162 xlb = L[(long)s * 64 + lane];
            lx[j] = bf2f(xlb.x);
            ly[j] = bf2f(xlb.y);
            float mx = lx[j] + xrx + wgt * wex;
            float my = ly[j] + xry + wgt * wey;
            mx = fmaxf(mx, 0.f) + 0.2f * fminf(mx, 0.f);
            my = fmaxf(my, 0.f) + 0.2f * fminf(my, 0.f);
            p[j] = mx * ax + my * ay;
        }
#pragma unroll
        for (int o = 1; o < 64; o <<= 1) {
#pragma unroll
            for (int j = 0; j < 4; ++j) p[j] += __shfl_xor(p[j], o, 64);
        }
#pragma unroll
        for (int j = 0; j < 4; ++j) {
            float ev = (base + j < cnt) ? __expf(p[j]) : 0.f;
            den += ev;
            accx += ev * lx[j];
            accy += ev * ly[j];
        }
    }
    float inv = 1.f / den;
    float vx = accx * inv + bias[c0] + resx;
    float vy = accy * inv + bias[c1] + resy;
    float s1 = vx + vy;
    for (int o = 1; o < 64; o <<= 1) s1 += __shfl_xor(s1, o, 64);
    float mu = s1 * (1.f / 128.f);
    float dx = vx - mu, dy = vy - mu;
    float s2 = dx * dx + dy * dy;
    for (int o = 1; o < 64; o <<= 1) s2 += __shfl_xor(s2, o, 64);
    float rstd = rsqrtf(s2 * (1.f / 128.f) + 1e-5f);
    float ox = dx * rstd * g[c0] + be[c0];
    float oy = dy * rstd * g[c1] + be[c1];
    if (ff) {
        ((float2*)out)[(long)v * 64 + lane] = make_float2(ox, oy);
    } else {
        __hip_bfloat162 ob;
        ob.x = __float2bfloat16(ox);
        ob.y = __float2bfloat16(oy);
        ((__hip_bfloat162*)out)[(long)v * 64 + lane] = ob;
    }
}

extern "C" void kernel_launch(void* const* d_in, const int* in_sizes, int n_in,
                              void* d_out, int out_size, void* d_ws, size_t ws_size,
                              hipStream_t stream) {
    const int n = in_sizes[0];
    const int E = in_sizes[1] / 2;
    const int* nid = (const int*)d_in[0];
    const int* eix = (const int*)d_in[1];
    const void* ew = d_in[2];

    char* base = (char*)d_ws;
    size_t off = 0;
    auto alloc = [&](size_t bytes) -> char* {
        size_t o = (off + 15) & ~(size_t)15;
        off = o + bytes;
        return base + o;
    };
    int*   flagf  = (int*)alloc(4);
    int*   flagi  = (int*)alloc(4);
    float* ew_sum = (float*)alloc(4);
    float* EWl    = (float*)alloc((size_t)D * D * 4);
    float* EWr    = (float*)alloc((size_t)D * D * 4);
    int*   offs     = (int*)alloc((size_t)(n + 1) * 4);
    int*   countcur = (int*)alloc((size_t)n * 4);  // counts, then cursor
    int*   bsum     = (int*)alloc(256 * 4);
    unsigned* csr   = (unsigned*)alloc((size_t)E * 4);
    bf16*  xl2    = (bf16*)alloc((size_t)n * D * 2);
    bf16*  xr2    = (bf16*)alloc((size_t)n * D * 2);

    CvArgs cv;
    float* P[NCV];
    for (int i = 0; i < NCV; ++i) {
        int sz = in_sizes[3 + i];
        P[i] = (float*)alloc((size_t)sz * 4);
        cv.s[i] = d_in[3 + i];
        cv.d[i] = P[i];
        cv.n[i] = sz;
    }
    float* emb_f = P[0];
    float* w1l = P[1], *b1l = P[2], *w1r = P[3], *b1r = P[4];
    float* w1e = P[5], *att1 = P[6], *bias1 = P[7], *g1 = P[8], *be1 = P[9];
    float* w2l = P[10], *b2l = P[11], *w2r = P[12], *b2r = P[13];
    float* w2e = P[14], *att2 = P[15], *bias2 = P[16], *g2 = P[17], *be2 = P[18];

    void* h1 = d_out;  // h1 lives in d_out (same dtype as final output either way)

    const float invE = 1.0f / (float)E;
    const int nb = (n + 255) / 256;

    k_detect_f<<<1, 256, 0, stream>>>(d_in[3], in_sizes[3], flagf, ew_sum);
    k_detect_i<<<1, 256, 0, stream>>>(eix, flagi);
    k_convert<<<NCV, 256, 0, stream>>>(cv, flagf);
    k_zeroi<<<nb, 256, 0, stream>>>(countcur, n);
    k_ew_sum<<<256, 256, 0, stream>>>(ew, E, flagf, ew_sum);
    k_tables<<<D, D, 0, stream>>>(emb_f, w1l, b1l, w1r, b1r, EWl, EWr);

    // ---- CSR build ----
    k_hist<<<512, 256, 0, stream>>>(eix, E, flagi, countcur);
    k_scan1<<<nb, 256, 0, stream>>>(countcur, n, offs, bsum);
    k_scan2<<<1, 256, 0, stream>>>(bsum, nb);
    k_scan3<<<nb, 256, 0, stream>>>(offs, bsum, n, E, countcur);
    k_scatter<<<512, 256, 0, stream>>>(eix, ew, E, flagf, flagi, countcur, csr);

    // ---- layer 1 (fused agg + LN) ----
    k_agg1<<<(n + 3) / 4, 256, 0, stream>>>(nid, offs, csr, EWl, EWr, emb_f,
                                            w1e, att1, bias1, g1, be1,
                                            ew_sum, invE, n, flagf, flagi, h1);
    // ---- layer 2 ----
    k_gemm2<<<(n + 15) / 16, 128, 0, stream>>>(h1, flagf, w2l, b2l, w2r, b2r, n, xl2, xr2);
    k_agg2<<<(n + 3) / 4, 256, 0, stream>>>(offs, csr, xl2, xr2, h1,
                                            w2e, att2, bias2, g2, be2,
                                            ew_sum, invE, n, flagf, d_out);
}